// Round 1
// baseline (296.801 us; speedup 1.0000x reference)
//
#include <hip/hip_runtime.h>

// One thread per row. State in registers; weights read through the scalar
// (uniform) path each step; trajectory records streamed out as float2 stores.

constexpr int kB     = 262144;
constexpr int kSteps = 15;

__device__ __forceinline__ float relu_(float v) { return fmaxf(v, 0.0f); }
__device__ __forceinline__ float sigmoid_(float v) {
    // 1/(1+exp(-v)); v_exp_f32 + v_rcp_f32, <=1ulp each — well inside tolerance.
    return __builtin_amdgcn_rcpf(1.0f + __expf(-v));
}

__global__ __launch_bounds__(256) void Program_4578435138231_kernel(
    const float* __restrict__ x,
    const float* __restrict__ c1w, const float* __restrict__ c1b,
    const float* __restrict__ c2w, const float* __restrict__ c2b,
    const float* __restrict__ l1w, const float* __restrict__ l1b,
    const float* __restrict__ l2w, const float* __restrict__ l2b,
    float* __restrict__ out)
{
    const int i = blockIdx.x * 256 + threadIdx.x;
    if (i >= kB) return;

    // ---- load row: 18 f32, base = i*72 B -> 8B-aligned, 9x float2 ----
    const float2* xr = reinterpret_cast<const float2*>(x + (size_t)i * 18);
    float s[18];
    #pragma unroll
    for (int j = 0; j < 9; ++j) {
        float2 v = xr[j];
        s[2 * j]     = v.x;
        s[2 * j + 1] = v.y;
    }

    const float cw10 = c1w[0], cw11 = c1w[1], cb1 = c1b[0];
    const float cw20 = c2w[0], cw21 = c2w[1], cb2 = c2b[0];

    // s[10] = distance
    {
        float dA = s[1] - s[3], dB = s[2] - s[4];
        s[10] = dA * dA + dB * dB;
    }

    float* orow = out + (size_t)i * 178;

    // traj0 = s[TRAJ_IDX] at offset 18 (even float index -> 8B aligned)
    {
        float2* tr = reinterpret_cast<float2*>(orow + 18);
        tr[0] = make_float2(s[10], s[1]);
        tr[1] = make_float2(s[2],  s[3]);
        tr[2] = make_float2(s[4],  s[5]);
        tr[3] = make_float2(s[6],  s[7]);
        tr[4] = make_float2(s[8],  s[17]);
    }

    #pragma unroll 1
    for (int t = 0; t < kSteps; ++t) {
        // ---- classifier on feat = s[[1,2,3,4,9,17]] ----
        float f0 = s[1], f1 = s[2], f2 = s[3], f3 = s[4], f4 = s[9], f5 = s[17];
        float h10 = relu_(cw10 * f0 + cw11 * f1 + cb1);
        float h11 = relu_(cw10 * f1 + cw11 * f2 + cb1);
        float h12 = relu_(cw10 * f2 + cw11 * f3 + cb1);
        float h13 = relu_(cw10 * f3 + cw11 * f4 + cb1);
        float h14 = relu_(cw10 * f4 + cw11 * f5 + cb1);
        float g0 = relu_(cw20 * h10 + cw21 * h11 + cb2);
        float g1 = relu_(cw20 * h11 + cw21 * h12 + cb2);
        float g2 = relu_(cw20 * h12 + cw21 * h13 + cb2);
        float g3 = relu_(cw20 * h13 + cw21 * h14 + cb2);

        float p0 = l2b[0], p1 = l2b[1], p2 = l2b[2], p3 = l2b[3], p4 = l2b[4];
        #pragma unroll
        for (int k = 0; k < 32; ++k) {
            float h = g0 * l1w[k] + g1 * l1w[32 + k] + g2 * l1w[64 + k]
                    + g3 * l1w[96 + k] + l1b[k];
            h = relu_(h);
            p0 += h * l2w[5 * k + 0];
            p1 += h * l2w[5 * k + 1];
            p2 += h * l2w[5 * k + 2];
            p3 += h * l2w[5 * k + 3];
            p4 += h * l2w[5 * k + 4];
        }
        p0 = sigmoid_(p0); p1 = sigmoid_(p1); p2 = sigmoid_(p2);
        p3 = sigmoid_(p3); p4 = sigmoid_(p4);

        s[5] = p0; s[6] = p1; s[7] = p2; s[8] = p3; s[17] = p4;
        float a = p1 - p0, b = p2 - p0, c = p3 - p0;
        float d = p2 - p1, e = p3 - p1, f = p3 - p2;
        s[11] = a; s[12] = b; s[13] = c; s[14] = d; s[15] = e; s[16] = f;

        float dx_c = (c <= 0.f) ? 0.f  : 5.f,  st_c = (c <= 0.f) ? 0.f : 3.f;
        float dx_f = (f <= 0.f) ? 0.f  : 5.f,  st_f = (f <= 0.f) ? 2.f : 3.f;
        float dx_e = (e <= 0.f) ? -5.f : 5.f,  st_e = (e <= 0.f) ? 1.f : 3.f;
        float dx_b = (b <= 0.f) ? dx_c : dx_f, st_b = (b <= 0.f) ? st_c : st_f;
        float dx_d = (d <= 0.f) ? dx_e : dx_f, st_d = (d <= 0.f) ? st_e : st_f;
        float dx   = (a <= 0.f) ? dx_b : dx_d, st   = (a <= 0.f) ? st_b : st_d;

        s[1] += dx; s[9] = st;
        s[2] += 5.f; s[3] += 5.f; s[0] += 1.f;
        float dA = s[1] - s[3], dB = s[2] - s[4];
        s[10] = dA * dA + dB * dB;

        // record s[TRAJ_IDX] (offset 18 + 10*(t+1), even -> 8B aligned)
        float2* tr = reinterpret_cast<float2*>(orow + 18 + 10 * (t + 1));
        tr[0] = make_float2(s[10], s[1]);
        tr[1] = make_float2(s[2],  s[3]);
        tr[2] = make_float2(s[4],  s[5]);
        tr[3] = make_float2(s[6],  s[7]);
        tr[4] = make_float2(s[8],  s[17]);
    }

    // final state s[0..17] at row start
    float2* os = reinterpret_cast<float2*>(orow);
    #pragma unroll
    for (int j = 0; j < 9; ++j) os[j] = make_float2(s[2 * j], s[2 * j + 1]);
}

extern "C" void kernel_launch(void* const* d_in, const int* in_sizes, int n_in,
                              void* d_out, int out_size, void* d_ws, size_t ws_size,
                              hipStream_t stream) {
    const float* x   = (const float*)d_in[0];
    const float* c1w = (const float*)d_in[1];
    const float* c1b = (const float*)d_in[2];
    const float* c2w = (const float*)d_in[3];
    const float* c2b = (const float*)d_in[4];
    const float* l1w = (const float*)d_in[5];
    const float* l1b = (const float*)d_in[6];
    const float* l2w = (const float*)d_in[7];
    const float* l2b = (const float*)d_in[8];
    float* out = (float*)d_out;

    Program_4578435138231_kernel<<<kB / 256, 256, 0, stream>>>(
        x, c1w, c1b, c2w, c2b, l1w, l1b, l2w, l2b, out);
}